// Round 1
// baseline (760.435 us; speedup 1.0000x reference)
//
#include <hip/hip_runtime.h>

#define HID 10
#define INP 64
#define STEPS 512

typedef __attribute__((ext_vector_type(8))) short v8s;   // 8 x bf16 (4 VGPRs)
typedef __attribute__((ext_vector_type(4))) float v4f;
typedef __attribute__((ext_vector_type(2))) float v2f;
typedef __attribute__((ext_vector_type(4))) int   v4i;

#define MFMA(A, Bf, C) __builtin_amdgcn_mfma_f32_16x16x32_bf16((A), (Bf), (C), 0, 0, 0)

static __device__ __forceinline__ v8s frag_from(unsigned d0, unsigned d1, unsigned d2, unsigned d3) {
    v4i t; t.x = (int)d0; t.y = (int)d1; t.z = (int)d2; t.w = (int)d3;
    return __builtin_bit_cast(v8s, t);
}
// pack two floats as truncated bf16 pair: low half = a, high half = b
static __device__ __forceinline__ unsigned pkhi(float a, float b) {
    return (__float_as_uint(a) >> 16) | (__float_as_uint(b) & 0xffff0000u);
}
static __device__ __forceinline__ float hif(float a) {
    return __uint_as_float(__float_as_uint(a) & 0xffff0000u);
}
// 8 floats -> hi frag (bf16-trunc) + lo frag (bf16-trunc of residual). Combined ~2^-16 rel.
static __device__ __forceinline__ void split8(const float* v, v8s& hi, v8s& lo) {
    hi = frag_from(pkhi(v[0], v[1]), pkhi(v[2], v[3]), pkhi(v[4], v[5]), pkhi(v[6], v[7]));
    float l0 = v[0] - hif(v[0]), l1 = v[1] - hif(v[1]);
    float l2 = v[2] - hif(v[2]), l3 = v[3] - hif(v[3]);
    float l4 = v[4] - hif(v[4]), l5 = v[5] - hif(v[5]);
    float l6 = v[6] - hif(v[6]), l7 = v[7] - hif(v[7]);
    lo = frag_from(pkhi(l0, l1), pkhi(l2, l3), pkhi(l4, l5), pkhi(l6, l7));
}
// read 8 contiguous f32 from LDS (8B-aligned), split into hi/lo bf16 frags
static __device__ __forceinline__ void read8_split(const float* p, v8s& hi, v8s& lo) {
    v2f p0 = *reinterpret_cast<const v2f*>(p);
    v2f p1 = *reinterpret_cast<const v2f*>(p + 2);
    v2f p2 = *reinterpret_cast<const v2f*>(p + 4);
    v2f p3 = *reinterpret_cast<const v2f*>(p + 6);
    float v[8] = {p0.x, p0.y, p1.x, p1.y, p2.x, p2.y, p3.x, p3.y};
    split8(v, hi, lo);
}

// Transposed formulation: all matmuls computed as (features x batch).
//   D[m][n] = sum_k A[m][k] B[k][n];  A = weights (constant frags), B = activations^T.
// A-frag: m = lane&15, k = (lane>>4)*8 + j   (verified layout, m89/m120)
// B-frag: n = lane&15, k = (lane>>4)*8 + j   (mirror, m92)
// C/D   : col(n=batch) = lane&15, row(m=feature) = (lane>>4)*4 + reg  (m89/m91)
__global__ __launch_bounds__(64, 1) void gru_decoder_kernel(
    const float* __restrict__ hidden, const float* __restrict__ w_ih,
    const float* __restrict__ w_hh, const float* __restrict__ b_ih,
    const float* __restrict__ b_hh, const float* __restrict__ l1_w,
    const float* __restrict__ l1_b, const float* __restrict__ l2_w,
    const float* __restrict__ l2_b, float* __restrict__ out)
{
    // per-wave LDS roundtrip buffers, [batch 16][feature], padded strides
    __shared__ float xbuf[16 * 68];   // x: 64 features
    __shared__ float hbuf[16 * 36];   // h: cols 0..15 live, 16..31 stay zero (K=32 pad)
    __shared__ float obuf[16 * 36];   // o: same

    const int lane = threadIdx.x;
    const int r15  = lane & 15;       // batch col for B/C frags; row m for A frags
    const int q    = lane >> 4;       // quad: k-group for A/B, row-group for C/D
    const int bg   = blockIdx.x * 16 + r15;   // global batch element

    // ---------------- preamble: constant A-frags (hi/lo split) ----------------
    v8s W1h[3][2], W1l[3][2];         // w_ih: 3 gates (r,z,n) x 2 K-chunks of 32
    #pragma unroll
    for (int g = 0; g < 3; ++g)
        #pragma unroll
        for (int c = 0; c < 2; ++c) {
            float v[8];
            #pragma unroll
            for (int j = 0; j < 8; ++j) {
                int k = c * 32 + q * 8 + j;
                v[j] = (r15 < 10) ? w_ih[(g * 10 + r15) * INP + k] : 0.f;
            }
            split8(v, W1h[g][c], W1l[g][c]);
        }
    v8s W2h[3], W2l[3];               // w_hh: K=10 padded to 32
    #pragma unroll
    for (int g = 0; g < 3; ++g) {
        float v[8];
        #pragma unroll
        for (int j = 0; j < 8; ++j) {
            int k = q * 8 + j;
            v[j] = (r15 < 10 && k < 10) ? w_hh[(g * 10 + r15) * HID + k] : 0.f;
        }
        split8(v, W2h[g], W2l[g]);
    }
    v8s L1h, L1l;                     // l1_w: 10x10 padded
    {
        float v[8];
        #pragma unroll
        for (int j = 0; j < 8; ++j) {
            int k = q * 8 + j;
            v[j] = (r15 < 10 && k < 10) ? l1_w[r15 * HID + k] : 0.f;
        }
        split8(v, L1h, L1l);
    }
    v8s L2h[4], L2l[4];               // l2_w: 64 rows -> 4 m-tiles, K=10 padded
    #pragma unroll
    for (int tt = 0; tt < 4; ++tt) {
        float v[8];
        #pragma unroll
        for (int j = 0; j < 8; ++j) {
            int k = q * 8 + j;
            v[j] = (k < 10) ? l2_w[(tt * 16 + r15) * HID + k] : 0.f;
        }
        split8(v, L2h[tt], L2l[tt]);
    }

    // bias frags (C-layout: feature f = q*4+i), used as initial C of each MFMA chain
    v4f Br, Bz, Bni, Bnh, Bo, Bx[4];
    #pragma unroll
    for (int i = 0; i < 4; ++i) {
        int f = q * 4 + i;
        Br[i]  = (f < 10) ? (b_ih[f]      + b_hh[f])      : 0.f;
        Bz[i]  = (f < 10) ? (b_ih[10 + f] + b_hh[10 + f]) : 0.f;
        Bni[i] = (f < 10) ? b_ih[20 + f] : 0.f;
        Bnh[i] = (f < 10) ? b_hh[20 + f] : 0.f;
        Bo[i]  = (f < 10) ? l1_b[f] : 0.f;
        #pragma unroll
        for (int tt = 0; tt < 4; ++tt) Bx[tt][i] = l2_b[tt * 16 + f];
    }

    // zero h/o buffers once: cols 16..31 provide the K=32 zero padding forever
    for (int idx = lane; idx < 16 * 36; idx += 64) { hbuf[idx] = 0.f; obuf[idx] = 0.f; }

    // initial hidden state in C-layout (rows >=10 are 0 and provably stay 0)
    v4f hC;
    #pragma unroll
    for (int i = 0; i < 4; ++i) {
        int f = q * 4 + i;
        hC[i] = (f < 10) ? hidden[bg * HID + f] : 0.f;
    }

    __syncthreads();
    *reinterpret_cast<v4f*>(&hbuf[r15 * 36 + q * 4]) = hC;
    __syncthreads();
    v8s hBh, hBl;
    read8_split(&hbuf[r15 * 36 + q * 8], hBh, hBl);

    v8s zf = frag_from(0u, 0u, 0u, 0u);
    v8s xBh[2], xBl[2];
    xBh[0] = xBh[1] = xBl[0] = xBl[1] = zf;   // x0 = 0

    float* outp = out + (size_t)bg * (STEPS * HID);

    #pragma unroll 1
    for (int t = 0; t < STEPS; ++t) {
        // ---- GI (x @ w_ih^T) + GH (h @ w_hh^T), r/z combined, n kept separate ----
        v4f Cr = MFMA(W1h[0][0], xBh[0], Br);
        Cr = MFMA(W1l[0][0], xBh[0], Cr);
        Cr = MFMA(W1h[0][0], xBl[0], Cr);
        Cr = MFMA(W1h[0][1], xBh[1], Cr);
        Cr = MFMA(W1l[0][1], xBh[1], Cr);
        Cr = MFMA(W1h[0][1], xBl[1], Cr);
        Cr = MFMA(W2h[0], hBh, Cr);
        Cr = MFMA(W2l[0], hBh, Cr);
        Cr = MFMA(W2h[0], hBl, Cr);

        v4f Cz = MFMA(W1h[1][0], xBh[0], Bz);
        Cz = MFMA(W1l[1][0], xBh[0], Cz);
        Cz = MFMA(W1h[1][0], xBl[0], Cz);
        Cz = MFMA(W1h[1][1], xBh[1], Cz);
        Cz = MFMA(W1l[1][1], xBh[1], Cz);
        Cz = MFMA(W1h[1][1], xBl[1], Cz);
        Cz = MFMA(W2h[1], hBh, Cz);
        Cz = MFMA(W2l[1], hBh, Cz);
        Cz = MFMA(W2h[1], hBl, Cz);

        v4f Cni = MFMA(W1h[2][0], xBh[0], Bni);
        Cni = MFMA(W1l[2][0], xBh[0], Cni);
        Cni = MFMA(W1h[2][0], xBl[0], Cni);
        Cni = MFMA(W1h[2][1], xBh[1], Cni);
        Cni = MFMA(W1l[2][1], xBh[1], Cni);
        Cni = MFMA(W1h[2][1], xBl[1], Cni);

        v4f Cnh = MFMA(W2h[2], hBh, Bnh);
        Cnh = MFMA(W2l[2], hBh, Cnh);
        Cnh = MFMA(W2h[2], hBl, Cnh);

        // ---- gates (fp32, lane-aligned in C-layout) ----
        #pragma unroll
        for (int i = 0; i < 4; ++i) {
            float rr = 1.f / (1.f + __expf(-Cr[i]));
            float zz = 1.f / (1.f + __expf(-Cz[i]));
            float y  = Cni[i] + rr * Cnh[i];
            float nn = 1.f - 2.f / (1.f + __expf(2.f * y));   // tanh(y)
            hC[i] = nn + zz * (hC[i] - nn);
        }

        // ---- h_new: C-layout -> B-frag (serves O now and GH next step) ----
        __syncthreads();
        *reinterpret_cast<v4f*>(&hbuf[r15 * 36 + q * 4]) = hC;
        __syncthreads();
        read8_split(&hbuf[r15 * 36 + q * 8], hBh, hBl);

        // ---- O = h_new @ l1_w^T + l1_b ----
        v4f Co = MFMA(L1h, hBh, Bo);
        Co = MFMA(L1l, hBh, Co);
        Co = MFMA(L1h, hBl, Co);

        // ---- store o at time (511 - t) (REVERSE) ----
        {
            float* po = outp + (size_t)(STEPS - 1 - t) * HID + q * 4;
            if (q < 3) {
                v2f s0; s0.x = Co[0]; s0.y = Co[1];
                *reinterpret_cast<v2f*>(po) = s0;
                if (q < 2) {
                    v2f s1; s1.x = Co[2]; s1.y = Co[3];
                    *reinterpret_cast<v2f*>(po + 2) = s1;
                }
            }
        }

        // ---- o: C-layout -> B-frag ----
        __syncthreads();
        *reinterpret_cast<v4f*>(&obuf[r15 * 36 + q * 4]) = Co;
        __syncthreads();
        v8s oBh, oBl;
        read8_split(&obuf[r15 * 36 + q * 8], oBh, oBl);

        // ---- x_next = o @ l2_w^T + l2_b (4 m-tiles of 16 features) ----
        v4f Cx[4];
        #pragma unroll
        for (int tt = 0; tt < 4; ++tt) {
            Cx[tt] = MFMA(L2h[tt], oBh, Bx[tt]);
            Cx[tt] = MFMA(L2l[tt], oBh, Cx[tt]);
            Cx[tt] = MFMA(L2h[tt], oBl, Cx[tt]);
        }

        // ---- x: C-layout -> 2 B-frags (K=64) for next step's GI ----
        __syncthreads();
        #pragma unroll
        for (int tt = 0; tt < 4; ++tt)
            *reinterpret_cast<v4f*>(&xbuf[r15 * 68 + tt * 16 + q * 4]) = Cx[tt];
        __syncthreads();
        #pragma unroll
        for (int c = 0; c < 2; ++c)
            read8_split(&xbuf[r15 * 68 + c * 32 + q * 8], xBh[c], xBl[c]);
    }
}

extern "C" void kernel_launch(void* const* d_in, const int* in_sizes, int n_in,
                              void* d_out, int out_size, void* d_ws, size_t ws_size,
                              hipStream_t stream) {
    (void)in_sizes; (void)n_in; (void)d_ws; (void)ws_size; (void)out_size;
    dim3 grid(512), block(64);   // 8192 batch / 16 per tile; 1 wave per tile
    gru_decoder_kernel<<<grid, block, 0, stream>>>(
        (const float*)d_in[0], (const float*)d_in[1], (const float*)d_in[2],
        (const float*)d_in[3], (const float*)d_in[4], (const float*)d_in[5],
        (const float*)d_in[6], (const float*)d_in[7], (const float*)d_in[8],
        (float*)d_out);
}

// Round 2
// 397.514 us; speedup vs baseline: 1.9130x; 1.9130x over previous
//
#include <hip/hip_runtime.h>

#define HID 10
#define INP 64
#define STEPS 512

typedef __attribute__((ext_vector_type(8))) short v8s;   // 8 x bf16 (4 VGPRs)
typedef __attribute__((ext_vector_type(4))) float v4f;
typedef __attribute__((ext_vector_type(2))) float v2f;
typedef __attribute__((ext_vector_type(4))) int   v4i;

#define MFMA(A, Bf, C) __builtin_amdgcn_mfma_f32_16x16x32_bf16((A), (Bf), (C), 0, 0, 0)

static __device__ __forceinline__ v8s frag_from(unsigned d0, unsigned d1, unsigned d2, unsigned d3) {
    v4i t; t.x = (int)d0; t.y = (int)d1; t.z = (int)d2; t.w = (int)d3;
    return __builtin_bit_cast(v8s, t);
}
static __device__ __forceinline__ unsigned pkhi(float a, float b) {
    return (__float_as_uint(a) >> 16) | (__float_as_uint(b) & 0xffff0000u);
}
static __device__ __forceinline__ float hif(float a) {
    return __uint_as_float(__float_as_uint(a) & 0xffff0000u);
}
// 8 floats -> hi frag (bf16-trunc) + lo frag (bf16-trunc of residual). Combined ~2^-16 rel.
static __device__ __forceinline__ void split8(const float* v, v8s& hi, v8s& lo) {
    hi = frag_from(pkhi(v[0], v[1]), pkhi(v[2], v[3]), pkhi(v[4], v[5]), pkhi(v[6], v[7]));
    float l0 = v[0] - hif(v[0]), l1 = v[1] - hif(v[1]);
    float l2 = v[2] - hif(v[2]), l3 = v[3] - hif(v[3]);
    float l4 = v[4] - hif(v[4]), l5 = v[5] - hif(v[5]);
    float l6 = v[6] - hif(v[6]), l7 = v[7] - hif(v[7]);
    lo = frag_from(pkhi(l0, l1), pkhi(l2, l3), pkhi(l4, l5), pkhi(l6, l7));
}

static __device__ __forceinline__ float bperm(int addr, float x) {
    return __int_as_float(__builtin_amdgcn_ds_bpermute(addr, __float_as_int(x)));
}

// h in C-layout (col=lane&15 batch, row=q*4+i) -> B-frag (n=lane&15, k=q*8+j), split bf16.
// Source of h[f][c]: lane (f>>2)*16+c, reg f&3. For target (q,j): f=q*8+j -> reg j&3 (uniform!),
// lane (q*2+(j>>2))*16+c. Rows 10..15 of h are exactly 0 by induction; q>=2 (k=16..31) zeroed.
static __device__ __forceinline__ void c_to_b(const v4f& hC, int q, int r15, v8s& hi, v8s& lo) {
    const int a0 = (((q * 2 + 0) * 16 + r15) & 63) * 4;
    const int a1 = (((q * 2 + 1) * 16 + r15) & 63) * 4;
    float v[8];
    v[0] = bperm(a0, hC[0]); v[1] = bperm(a0, hC[1]);
    v[2] = bperm(a0, hC[2]); v[3] = bperm(a0, hC[3]);
    v[4] = bperm(a1, hC[0]); v[5] = bperm(a1, hC[1]);
    v[6] = bperm(a1, hC[2]); v[7] = bperm(a1, hC[3]);
    #pragma unroll
    for (int j = 0; j < 8; ++j) v[j] = (q < 2) ? v[j] : 0.f;
    split8(v, hi, lo);
}

static __device__ __forceinline__ v4f chain3(v8s Ah, v8s Al, v8s Bh, v8s Bl, v4f C) {
    C = MFMA(Ah, Bh, C);
    C = MFMA(Al, Bh, C);
    C = MFMA(Ah, Bl, C);
    return C;
}

// sigmoid/tanh with log2e prefolded into weights: r=rcp(1+exp2(-Cr)), n=1-2*rcp(1+exp2(y))
static __device__ __forceinline__ void gate_update(const v4f& Cr, const v4f& Cz,
                                                   const v4f& Cni, const v4f& Cnh, v4f& hC) {
    #pragma unroll
    for (int i = 0; i < 4; ++i) {
        float r = __builtin_amdgcn_rcpf(1.f + __builtin_amdgcn_exp2f(-Cr[i]));
        float z = __builtin_amdgcn_rcpf(1.f + __builtin_amdgcn_exp2f(-Cz[i]));
        float y = Cni[i] + r * Cnh[i];
        float n = 1.f - 2.f * __builtin_amdgcn_rcpf(1.f + __builtin_amdgcn_exp2f(y));
        hC[i] = n + z * (hC[i] - n);
    }
}

// Fused recurrence: x_t = l2(l1(h_t)) is linear =>
//   gi_t = Wgi @ h_t + b_gi  (t>=1),  Wgi = w_ih@l2_w@l1_w (30x10), b_gi = b_ih + w_ih@(l2_w@l1_b+l2_b)
//   gates = (Wgi+w_hh) @ h + biases (r,z merged); n_i from Wgi only, n_h from w_hh only.
// o_t = l1_w @ h_{t+1} + l1_b is OFF the critical path (store only).
// t=0 peeled: gi_0 = b_ih (x_0 = 0).
__global__ __launch_bounds__(64, 1) void gru_decoder_kernel(
    const float* __restrict__ hidden, const float* __restrict__ w_ih,
    const float* __restrict__ w_hh, const float* __restrict__ b_ih,
    const float* __restrict__ b_hh, const float* __restrict__ l1_w,
    const float* __restrict__ l1_b, const float* __restrict__ l2_w,
    const float* __restrict__ l2_b, float* __restrict__ out)
{
    __shared__ float sWx[640];   // (l2_w @ l1_w), 64x10
    __shared__ float sbx[64];    // l2_w @ l1_b + l2_b
    __shared__ float sWgi[300];  // w_ih @ Wx, 30x10
    __shared__ float sbgi[30];   // b_ih + w_ih @ bx

    const int lane = threadIdx.x;
    const int r15  = lane & 15;
    const int q    = lane >> 4;
    const int bg   = blockIdx.x * 16 + r15;

    // ---- preamble: fused weights (fp32, cooperative) ----
    for (int e = lane; e < 640; e += 64) {
        int i = e / 10, j = e - i * 10;
        float acc = 0.f;
        #pragma unroll
        for (int k = 0; k < 10; ++k) acc += l2_w[i * 10 + k] * l1_w[k * 10 + j];
        sWx[e] = acc;
    }
    {
        float acc = l2_b[lane];
        #pragma unroll
        for (int k = 0; k < 10; ++k) acc += l2_w[lane * 10 + k] * l1_b[k];
        sbx[lane] = acc;
    }
    __syncthreads();
    for (int e = lane; e < 300; e += 64) {
        int m = e / 10, j = e - m * 10;
        float acc = 0.f;
        for (int k = 0; k < 64; ++k) acc += w_ih[m * 64 + k] * sWx[k * 10 + j];
        sWgi[e] = acc;
    }
    if (lane < 30) {
        float acc = b_ih[lane];
        for (int k = 0; k < 64; ++k) acc += w_ih[lane * 64 + k] * sbx[k];
        sbgi[lane] = acc;
    }
    __syncthreads();

    const float LOG2E = 1.4426950408889634f;
    const float S2    = 2.f * LOG2E;

    // ---- constant A-frags (m=r15, k=q*8+j), hi/lo split, log2e prefolded ----
    v8s Wrh, Wrl, Wzh, Wzl, Wnih, Wnil, Wnhh, Wnhl, L1h, L1l, Prh, Prl, Pzh, Pzl;
    {
        float vr[8], vz[8], vni[8], vnh[8], vl1[8], vpr[8], vpz[8];
        #pragma unroll
        for (int j = 0; j < 8; ++j) {
            int k = q * 8 + j;
            float wpr = 0.f, wpz = 0.f, wnh = 0.f, wr = 0.f, wz = 0.f, wni = 0.f, wl1 = 0.f;
            if (r15 < 10 && k < 10) {
                wpr = w_hh[r15 * 10 + k];
                wpz = w_hh[(10 + r15) * 10 + k];
                wnh = w_hh[(20 + r15) * 10 + k];
                wr  = sWgi[r15 * 10 + k] + wpr;
                wz  = sWgi[(10 + r15) * 10 + k] + wpz;
                wni = sWgi[(20 + r15) * 10 + k];
                wl1 = l1_w[r15 * 10 + k];
            }
            vr[j] = wr * LOG2E; vz[j] = wz * LOG2E;
            vni[j] = wni * S2;  vnh[j] = wnh * S2;
            vl1[j] = wl1;
            vpr[j] = wpr * LOG2E; vpz[j] = wpz * LOG2E;
        }
        split8(vr, Wrh, Wrl); split8(vz, Wzh, Wzl);
        split8(vni, Wnih, Wnil); split8(vnh, Wnhh, Wnhl);
        split8(vl1, L1h, L1l);
        split8(vpr, Prh, Prl); split8(vpz, Pzh, Pzl);
    }

    // ---- bias frags (C layout: f=q*4+i) ----
    v4f Br, Bz, Bni, Bnh, Bo, Br0, Bz0, Bni0;
    #pragma unroll
    for (int i = 0; i < 4; ++i) {
        int f = q * 4 + i;
        bool ok = f < 10;
        Br[i]   = ok ? (sbgi[f] + b_hh[f]) * LOG2E : 0.f;
        Bz[i]   = ok ? (sbgi[10 + f] + b_hh[10 + f]) * LOG2E : 0.f;
        Bni[i]  = ok ? sbgi[20 + f] * S2 : 0.f;
        Bnh[i]  = ok ? b_hh[20 + f] * S2 : 0.f;
        Bo[i]   = ok ? l1_b[f] : 0.f;
        Br0[i]  = ok ? (b_ih[f] + b_hh[f]) * LOG2E : 0.f;
        Bz0[i]  = ok ? (b_ih[10 + f] + b_hh[10 + f]) * LOG2E : 0.f;
        Bni0[i] = ok ? b_ih[20 + f] * S2 : 0.f;
    }

    // ---- initial h (rows >= 10 are 0 and stay 0 exactly) ----
    v4f hC;
    #pragma unroll
    for (int i = 0; i < 4; ++i) {
        int f = q * 4 + i;
        hC[i] = (f < 10) ? hidden[bg * HID + f] : 0.f;
    }
    v8s hBh, hBl;
    c_to_b(hC, q, r15, hBh, hBl);

    float* po = out + (size_t)bg * (STEPS * HID) + (size_t)(STEPS - 1) * HID;

    // ---- t = 0 (peeled: gi = b_ih only) ----
    {
        v4f Cr  = chain3(Prh, Prl, hBh, hBl, Br0);
        v4f Cz  = chain3(Pzh, Pzl, hBh, hBl, Bz0);
        v4f Cnh = chain3(Wnhh, Wnhl, hBh, hBl, Bnh);
        gate_update(Cr, Cz, Bni0, Cnh, hC);
        c_to_b(hC, q, r15, hBh, hBl);
        v4f Co = chain3(L1h, L1l, hBh, hBl, Bo);
        if (q < 3) {
            v2f s0; s0.x = Co[0]; s0.y = Co[1];
            *reinterpret_cast<v2f*>(po + q * 4) = s0;
            if (q < 2) {
                v2f s1; s1.x = Co[2]; s1.y = Co[3];
                *reinterpret_cast<v2f*>(po + q * 4 + 2) = s1;
            }
        }
        po -= HID;
    }

    // ---- t = 1 .. 511 ----
    #pragma unroll 1
    for (int t = 1; t < STEPS; ++t) {
        v4f Cr  = chain3(Wrh, Wrl, hBh, hBl, Br);
        v4f Cz  = chain3(Wzh, Wzl, hBh, hBl, Bz);
        v4f Cni = chain3(Wnih, Wnil, hBh, hBl, Bni);
        v4f Cnh = chain3(Wnhh, Wnhl, hBh, hBl, Bnh);
        gate_update(Cr, Cz, Cni, Cnh, hC);
        c_to_b(hC, q, r15, hBh, hBl);
        v4f Co = chain3(L1h, L1l, hBh, hBl, Bo);
        if (q < 3) {
            v2f s0; s0.x = Co[0]; s0.y = Co[1];
            *reinterpret_cast<v2f*>(po + q * 4) = s0;
            if (q < 2) {
                v2f s1; s1.x = Co[2]; s1.y = Co[3];
                *reinterpret_cast<v2f*>(po + q * 4 + 2) = s1;
            }
        }
        po -= HID;
    }
}

extern "C" void kernel_launch(void* const* d_in, const int* in_sizes, int n_in,
                              void* d_out, int out_size, void* d_ws, size_t ws_size,
                              hipStream_t stream) {
    (void)in_sizes; (void)n_in; (void)d_ws; (void)ws_size; (void)out_size;
    dim3 grid(512), block(64);   // 8192 batch / 16 per wave-tile
    gru_decoder_kernel<<<grid, block, 0, stream>>>(
        (const float*)d_in[0], (const float*)d_in[1], (const float*)d_in[2],
        (const float*)d_in[3], (const float*)d_in[4], (const float*)d_in[5],
        (const float*)d_in[6], (const float*)d_in[7], (const float*)d_in[8],
        (float*)d_out);
}